// Round 8
// baseline (260.636 us; speedup 1.0000x reference)
//
#include <hip/hip_runtime.h>

#define NPT   4096
#define KNN_K 16
#define EPSV  1e-5f

// ---- ws float layout ----
#define W1T_OFF 4352               // [64][64]  (ic-major)
#define B1_OFF  8448               // [64]
#define W2T_OFF 8512               // [64][128] (ic-major)
#define B2_OFF  16704              // [128]
#define IDX_OFF 16832              // int[4*4096*16]
#define P_OFF   344512             // float[16384][64]  P = W0p*pts + W0x*xyz + b0
#define Q_OFF   1393088            // float[16384][64]  Q = W0x*xyz

typedef unsigned long long ull;

__device__ __forceinline__ ull minu64(ull a, ull b) { return a < b ? a : b; }
__device__ __forceinline__ ull maxu64(ull a, ull b) { return a > b ? a : b; }

__device__ __forceinline__ ull bitonic_sort64(ull v, int lane) {
#pragma unroll
  for (int k = 2; k <= 64; k <<= 1) {
#pragma unroll
    for (int j = k >> 1; j > 0; j >>= 1) {
      ull o = __shfl_xor(v, j);
      bool lower = (lane & j) == 0;
      bool up = (lane & k) == 0;
      v = (lower == up) ? minu64(v, o) : maxu64(v, o);
    }
  }
  return v;
}

__device__ __forceinline__ ull bitonic_merge64(ull v, int lane) {
#pragma unroll
  for (int j = 32; j > 0; j >>= 1) {
    ull o = __shfl_xor(v, j);
    v = ((lane & j) == 0) ? minu64(v, o) : maxu64(v, o);
  }
  return v;
}

// MEGA kernel v10: v9 dispatch frame (knn first -> dense CU packing) + v8's
// slimmed knn inner loop (isolated this time): u32 threshold compare
// (fk<=thresh_hi admits a superset of the exact u64 test; flush merge still
// selects the identical top-16 by full u64 order), mbcnt prefix-popcount,
// u64 key pack only under if(mask).
//   blocks [0,4096):    KNN (long pole, dispatched FIRST)
//   blocks [4096,6144): P/Q, 2 points/wave
//   blocks [6144,6193): W1/W2/bias fold for mlp
__global__ __launch_bounds__(256) void mega_kernel(
    const float* __restrict__ xyz, const float* __restrict__ points,
    const float* __restrict__ w0, const float* __restrict__ b0, const float* __restrict__ g0,
    const float* __restrict__ be0, const float* __restrict__ rm0, const float* __restrict__ rv0,
    const float* __restrict__ w1, const float* __restrict__ b1, const float* __restrict__ g1,
    const float* __restrict__ be1, const float* __restrict__ rm1, const float* __restrict__ rv1,
    const float* __restrict__ w2, const float* __restrict__ b2, const float* __restrict__ g2,
    const float* __restrict__ be2, const float* __restrict__ rm2, const float* __restrict__ rv2,
    float* __restrict__ ws, int* __restrict__ knnOut) {
  __shared__ __align__(16) unsigned char smem[20480];  // knn: 16K tile + 4K buf; pq: 17.2K w0
  int blk = blockIdx.x;
  int tid = threadIdx.x;

  if (blk < 4096) {
    // ---------------- KNN: wave/query threshold-filter + bitonic flush ----
    float4* tile = (float4*)smem;                 // [1024] candidate (x,y,z,sq)
    ull* buf = (ull*)(smem + 16384);              // [4][128]
    int lane = tid & 63, w = tid >> 6;
    int b = blk >> 10;
    int n = ((blk & 1023) << 2) + w;
    const float* xb = xyz + (size_t)b * NPT * 3;

    float4 q;
    {
      const float* qp = xb + n * 3;
      float qx = qp[0], qy = qp[1], qz = qp[2];
      float qsq = __fadd_rn(__fadd_rn(__fmul_rn(qx, qx), __fmul_rn(qy, qy)),
                            __fmul_rn(qz, qz));
      q = make_float4(qx, qy, qz, qsq);
    }
    ull R = ~0ull;
    unsigned thresh_hi = 0xFFFFFFFFu;
    int cnt = 0;
    const float4* r4 = (const float4*)xb;         // batch base, 16B-aligned

#pragma unroll 1
    for (int t = 0; t < 4; ++t) {
      __syncthreads();
      {
        // stage 1024 candidates from raw xyz: 3 coalesced float4 loads = 4 cands
        int fo = 768 * t + 3 * tid;
        float4 A = r4[fo], B = r4[fo + 1], C = r4[fo + 2];
        float xs[4] = {A.x, A.w, B.z, C.y};
        float ys[4] = {A.y, B.x, B.w, C.z};
        float zs[4] = {A.z, B.y, C.x, C.w};
#pragma unroll
        for (int j = 0; j < 4; ++j) {
          float sq = __fadd_rn(__fadd_rn(__fmul_rn(xs[j], xs[j]), __fmul_rn(ys[j], ys[j])),
                               __fmul_rn(zs[j], zs[j]));
          tile[4 * tid + j] = make_float4(xs[j], ys[j], zs[j], sq);
        }
      }
      __syncthreads();
#pragma unroll 1
      for (int i = 0; i < 16; ++i) {
        float4 c = tile[(i << 6) + lane];
        float dot = __fadd_rn(__fadd_rn(__fmul_rn(q.x, c.x), __fmul_rn(q.y, c.y)),
                              __fmul_rn(q.z, c.z));
        float d2 = __fsub_rn(__fadd_rn(q.w, c.w), __fmul_rn(2.0f, dot));
        unsigned bits = __float_as_uint(d2);
        unsigned fk = bits ^ (0x80000000u | (unsigned)((int)bits >> 31));
        bool pred = fk <= thresh_hi;
        ull mask = __ballot(pred);
        if (mask) {
          int pos = cnt + (int)__builtin_amdgcn_mbcnt_hi(
                              (unsigned)(mask >> 32),
                              __builtin_amdgcn_mbcnt_lo((unsigned)mask, 0u));
          if (pred)
            buf[w * 128 + pos] =
                ((ull)fk << 32) | (unsigned)((t << 10) + (i << 6) + lane);
          cnt += __popcll(mask);
          if (cnt >= 64) {
            ull v = buf[w * 128 + lane];
            v = bitonic_sort64(v, lane);
            ull vr = __shfl(v, 63 - lane);
            R = minu64(R, vr);
            R = bitonic_merge64(R, lane);
            thresh_hi = (unsigned)__shfl((int)(unsigned)(R >> 32), 15);
            cnt -= 64;
            if (lane < cnt) {
              ull tmp = buf[w * 128 + 64 + lane];
              buf[w * 128 + lane] = tmp;
            }
          }
        }
      }
    }
    {
      ull v = (lane < cnt) ? buf[w * 128 + lane] : ~0ull;
      v = bitonic_sort64(v, lane);
      ull vr = __shfl(v, 63 - lane);
      R = minu64(R, vr);
      R = bitonic_merge64(R, lane);
    }
    if (lane < KNN_K)
      knnOut[(b * NPT + n) * KNN_K + lane] = (int)(unsigned)(R & 0xFFFFFFFFull);
    return;
  }

  if (blk < 6144) {
    // ---------------- P/Q precompute: 2 points per wave ------------------
    float* wlds = (float*)smem;                   // [64*67] folded w0
    for (int j = tid; j < 4288; j += 256) {
      int r = j / 67;
      float s = g0[r] * rsqrtf(rv0[r] + EPSV);
      wlds[j] = __fmul_rn(w0[j], s);
    }
    __syncthreads();
    int oc = tid & 63;
    int base = (blk - 4096) * 8 + (tid >> 6);
    float s = g0[oc] * rsqrtf(rv0[oc] + EPSV);
    float b0f = (b0[oc] - rm0[oc]) * s + be0[oc];
    const float* wrow = wlds + oc * 67;           // stride-67 -> 2-way bank (free)
#pragma unroll 1
    for (int pt = 0; pt < 2; ++pt) {
      int i = base + pt * 4;
      float x = xyz[i * 3], y = xyz[i * 3 + 1], z = xyz[i * 3 + 2];
      float qacc = wrow[0] * x;
      qacc = fmaf(wrow[1], y, qacc);
      qacc = fmaf(wrow[2], z, qacc);
      float acc = b0f + qacc;
      const float* prow = points + (size_t)i * 64;
#pragma unroll 4
      for (int c = 0; c < 64; ++c) acc = fmaf(wrow[3 + c], prow[c], acc);
      ws[P_OFF + (size_t)i * 64 + oc] = acc;
      ws[Q_OFF + (size_t)i * 64 + oc] = qacc;
    }
    return;
  }

  // ---------------- weight fold for mlp (W1T/B1/W2T/B2) ------------------
  {
    int i = (blk - 6144) * 256 + tid + 4352;
    if (i < 8448) {
      int j = i - 4352; int oc = j & 63, ic = j >> 6;
      float s = g1[oc] * rsqrtf(rv1[oc] + EPSV);
      ws[i] = w1[oc * 64 + ic] * s;
    } else if (i < 8512) {
      int oc = i - 8448;
      float s = g1[oc] * rsqrtf(rv1[oc] + EPSV);
      ws[i] = (b1[oc] - rm1[oc]) * s + be1[oc];
    } else if (i < 16704) {
      int j = i - 8512; int ic = j >> 7, oc = j & 127;
      float s = g2[oc] * rsqrtf(rv2[oc] + EPSV);
      ws[i] = w2[oc * 64 + ic] * s;               // w2t [ic][oc]
    } else if (i < 16832) {
      int oc = i - 16704;
      float s = g2[oc] * rsqrtf(rv2[oc] + EPSV);
      ws[i] = (b2[oc] - rm2[oc]) * s + be2[oc];
    }
  }
}

// MLP v10: block = 256 thr = 8 queries = 128 pairs.
// Layer 1: 4p x 8oc tile (as v8). Layer 2: SINGLE pass over all 128 oc with
// 8p x 8oc tiles (256 thr = 16 pgrp x 16 ogrp) -> 4 ds_read_b128 per 64 FMA
// (v8 L2 was 6 per 64). W2 chunked [32ic][128oc] (16 KB). LDS 32+16 = 48 KB
// -> 3 blocks/CU (3 waves/SIMD, enough to hide LDS latency per v6).
// Barriers 11 -> 7. Accumulation order bias + ic 0..63 -> bit-identical.
__global__ __launch_bounds__(256, 3) void mlp_kernel(
    const float* __restrict__ wbuf, const int* __restrict__ knn,
    float* __restrict__ out) {
  __shared__ __align__(16) float Ash[64 * 128];   // 32 KB [ic][p]
  __shared__ __align__(16) float Wsh[32 * 128];   // 16 KB (W1 chunks use 1st 8 KB)
  int tid = threadIdx.x;
  int qblk = blockIdx.x << 3;                     // 8 flat queries per block

  const float4* w1g = (const float4*)(wbuf + W1T_OFF);   // [64][16 f4]
  const float4* w2g = (const float4*)(wbuf + W2T_OFF);   // [64][32 f4]
  float4* wl = (float4*)Wsh;

  // W2 chunk h (ic-half): entry e in [0,1024) f4 -> global row 32h+(e>>5), colf4 e&31
#define W2C(e, h) ((((h) << 5) + ((e) >> 5)) * 32 + ((e) & 31))

  // ---- preload W1a ----
  float4 s0 = w1g[tid];
  float4 s1 = w1g[256 + tid];
  float4 s2, s3;

  // ---- h0: pair p = tid&127, ic-half = tid>>7 ----
  {
    int p = tid & 127, half = tid >> 7;
    int q = qblk + (p >> 4);
    int k = p & 15;
    int src = knn[q * KNN_K + k];                 // coalesced across 128 threads
    int srow = (q & ~(NPT - 1)) + src;
    const float4* Pp = (const float4*)(wbuf + P_OFF + (size_t)srow * 64 + half * 32);
    const float4* Qp = (const float4*)(wbuf + Q_OFF + (size_t)q * 64 + half * 32);
#pragma unroll
    for (int j = 0; j < 8; ++j) {
      float4 pv = Pp[j];
      float4 qv = Qp[j];
      int ic = half * 32 + j * 4;
      Ash[(ic + 0) * 128 + p] = fmaxf(pv.x - qv.x, 0.0f);
      Ash[(ic + 1) * 128 + p] = fmaxf(pv.y - qv.y, 0.0f);
      Ash[(ic + 2) * 128 + p] = fmaxf(pv.z - qv.z, 0.0f);
      Ash[(ic + 3) * 128 + p] = fmaxf(pv.w - qv.w, 0.0f);
    }
  }
  // write W1a; preload W1b
  wl[tid] = s0; wl[256 + tid] = s1;
  s0 = w1g[512 + tid]; s1 = w1g[768 + tid];
  __syncthreads();                                 // S1: h0 + W1a visible

  int og = tid & 7, pg = tid >> 3;                 // L1: 32 pgrp x 8 ogrp
  const float* Arow = Ash + 4 * pg;
  const float* Wrow = Wsh + 8 * og;
  float acc[8][8];                                 // L1 uses [0..3][..]

#define GEMM32(R0)                                                        \
  _Pragma("unroll 8")                                                     \
  for (int ic = 0; ic < 32; ++ic) {                                       \
    float4 a0 = *(const float4*)(Arow + ((R0) + ic) * 128);               \
    float4 wv0 = *(const float4*)(Wrow + ic * 64);                        \
    float4 wv1 = *(const float4*)(Wrow + ic * 64 + 4);                    \
    float av[4] = {a0.x, a0.y, a0.z, a0.w};                               \
    float wv[8] = {wv0.x, wv0.y, wv0.z, wv0.w, wv1.x, wv1.y, wv1.z, wv1.w};\
    _Pragma("unroll")                                                     \
    for (int ii = 0; ii < 4; ++ii)                                        \
      _Pragma("unroll")                                                   \
      for (int jj = 0; jj < 8; ++jj) acc[ii][jj] = fmaf(av[ii], wv[jj], acc[ii][jj]); \
  }

  // ---- layer 1 ----
  {
    float4 b0v = *(const float4*)(wbuf + B1_OFF + 8 * og);
    float4 b1v = *(const float4*)(wbuf + B1_OFF + 8 * og + 4);
    float bj[8] = {b0v.x, b0v.y, b0v.z, b0v.w, b1v.x, b1v.y, b1v.z, b1v.w};
#pragma unroll
    for (int i = 0; i < 4; ++i)
#pragma unroll
      for (int j = 0; j < 8; ++j) acc[i][j] = bj[j];
  }
  GEMM32(0)                                        // W1a: ic 0..31
  __syncthreads();                                 // S2: W1a reads done
  wl[tid] = s0; wl[256 + tid] = s1;                // write W1b
  s0 = w2g[W2C(tid, 0)];       s1 = w2g[W2C(tid + 256, 0)];
  s2 = w2g[W2C(tid + 512, 0)]; s3 = w2g[W2C(tid + 768, 0)];
  __syncthreads();                                 // S3: W1b visible
  GEMM32(32)                                       // W1b: ic 32..63
  __syncthreads();                                 // S4: all h0 + W1b reads done

  // h1 -> A[oc][p]
#pragma unroll
  for (int j = 0; j < 8; ++j) {
    int oc = 8 * og + j;
    *(float4*)(Ash + oc * 128 + 4 * pg) =
        make_float4(fmaxf(acc[0][j], 0.0f), fmaxf(acc[1][j], 0.0f),
                    fmaxf(acc[2][j], 0.0f), fmaxf(acc[3][j], 0.0f));
  }
  // write W2 chunk0; preload chunk1
  wl[tid] = s0; wl[256 + tid] = s1; wl[512 + tid] = s2; wl[768 + tid] = s3;
  s0 = w2g[W2C(tid, 1)];       s1 = w2g[W2C(tid + 256, 1)];
  s2 = w2g[W2C(tid + 512, 1)]; s3 = w2g[W2C(tid + 768, 1)];
  __syncthreads();                                 // S5: h1 + W2c0 visible

  // ---- layer 2: single pass, 128 oc, 8p x 8oc per thread ----
  int og2 = tid & 15, pg2 = tid >> 4;              // 16 pgrp x 16 ogrp
  const float* Arow2 = Ash + 8 * pg2;
  const float* Wrow2 = Wsh + 8 * og2;

#define GEMM32L2(R0)                                                      \
  _Pragma("unroll 4")                                                     \
  for (int ic = 0; ic < 32; ++ic) {                                       \
    float4 a0 = *(const float4*)(Arow2 + ((R0) + ic) * 128);              \
    float4 a1 = *(const float4*)(Arow2 + ((R0) + ic) * 128 + 4);          \
    float4 wv0 = *(const float4*)(Wrow2 + ic * 128);                      \
    float4 wv1 = *(const float4*)(Wrow2 + ic * 128 + 4);                  \
    float av[8] = {a0.x, a0.y, a0.z, a0.w, a1.x, a1.y, a1.z, a1.w};       \
    float wv[8] = {wv0.x, wv0.y, wv0.z, wv0.w, wv1.x, wv1.y, wv1.z, wv1.w};\
    _Pragma("unroll")                                                     \
    for (int ii = 0; ii < 8; ++ii)                                        \
      _Pragma("unroll")                                                   \
      for (int jj = 0; jj < 8; ++jj) acc[ii][jj] = fmaf(av[ii], wv[jj], acc[ii][jj]); \
  }

  {
    float4 b0v = *(const float4*)(wbuf + B2_OFF + 8 * og2);
    float4 b1v = *(const float4*)(wbuf + B2_OFF + 8 * og2 + 4);
    float bj[8] = {b0v.x, b0v.y, b0v.z, b0v.w, b1v.x, b1v.y, b1v.z, b1v.w};
#pragma unroll
    for (int i = 0; i < 8; ++i)
#pragma unroll
      for (int j = 0; j < 8; ++j) acc[i][j] = bj[j];
  }
  GEMM32L2(0)                                      // W2c0: ic 0..31
  __syncthreads();                                 // S6: W2c0 reads done
  wl[tid] = s0; wl[256 + tid] = s1; wl[512 + tid] = s2; wl[768 + tid] = s3;
  __syncthreads();                                 // S7: W2c1 visible
  GEMM32L2(32)                                     // W2c1: ic 32..63

  // relu + max over 8 in-thread pairs (k 0..7 or 8..15), then pg2^1 partner
  {
    int qout = qblk + (pg2 >> 1);
    float* obase = out + (size_t)qout * 128 + 8 * og2;
    float m[8];
#pragma unroll
    for (int j = 0; j < 8; ++j) {
      float v = fmaxf(fmaxf(fmaxf(acc[0][j], acc[1][j]), fmaxf(acc[2][j], acc[3][j])),
                      fmaxf(fmaxf(acc[4][j], acc[5][j]), fmaxf(acc[6][j], acc[7][j])));
      v = fmaxf(v, 0.0f);
      m[j] = fmaxf(v, __shfl_xor(v, 16));          // pg2 bit 0 (tid bit 4)
    }
    if ((pg2 & 1) == 0) {
      *(float4*)(obase)     = make_float4(m[0], m[1], m[2], m[3]);
      *(float4*)(obase + 4) = make_float4(m[4], m[5], m[6], m[7]);
    }
  }
#undef GEMM32
#undef GEMM32L2
#undef W2C
}

extern "C" void kernel_launch(void* const* d_in, const int* in_sizes, int n_in,
                              void* d_out, int out_size, void* d_ws, size_t ws_size,
                              hipStream_t stream) {
  const float* xyz    = (const float*)d_in[0];
  const float* points = (const float*)d_in[1];
  float* wsF = (float*)d_ws;
  int* idxBuf = (int*)(wsF + IDX_OFF);

  mega_kernel<<<6193, 256, 0, stream>>>(
      xyz, points,
      (const float*)d_in[2],  (const float*)d_in[3],  (const float*)d_in[4],
      (const float*)d_in[5],  (const float*)d_in[6],  (const float*)d_in[7],
      (const float*)d_in[8],  (const float*)d_in[9],  (const float*)d_in[10],
      (const float*)d_in[11], (const float*)d_in[12], (const float*)d_in[13],
      (const float*)d_in[14], (const float*)d_in[15], (const float*)d_in[16],
      (const float*)d_in[17], (const float*)d_in[18], (const float*)d_in[19],
      wsF, idxBuf);
  mlp_kernel<<<2048, 256, 0, stream>>>(wsF, idxBuf, (float*)d_out);
}

// Round 9
// 257.235 us; speedup vs baseline: 1.0132x; 1.0132x over previous
//
#include <hip/hip_runtime.h>

#define NPT   4096
#define KNN_K 16
#define EPSV  1e-5f

// ---- ws float layout ----
#define W1T_OFF 4352               // [64][64]  (ic-major)
#define B1_OFF  8448               // [64]
#define W2T_OFF 8512               // [64][128] (ic-major)
#define B2_OFF  16704              // [128]
#define IDX_OFF 16832              // int[4*4096*16]
#define P_OFF   344512             // float[16384][64]  P = W0p*pts + W0x*xyz + b0
#define Q_OFF   1393088            // float[16384][64]  Q = W0x*xyz

typedef unsigned long long ull;

__device__ __forceinline__ ull minu64(ull a, ull b) { return a < b ? a : b; }
__device__ __forceinline__ ull maxu64(ull a, ull b) { return a > b ? a : b; }

__device__ __forceinline__ ull bitonic_sort64(ull v, int lane) {
#pragma unroll
  for (int k = 2; k <= 64; k <<= 1) {
#pragma unroll
    for (int j = k >> 1; j > 0; j >>= 1) {
      ull o = __shfl_xor(v, j);
      bool lower = (lane & j) == 0;
      bool up = (lane & k) == 0;
      v = (lower == up) ? minu64(v, o) : maxu64(v, o);
    }
  }
  return v;
}

__device__ __forceinline__ ull bitonic_merge64(ull v, int lane) {
#pragma unroll
  for (int j = 32; j > 0; j >>= 1) {
    ull o = __shfl_xor(v, j);
    v = ((lane & j) == 0) ? minu64(v, o) : maxu64(v, o);
  }
  return v;
}

// One filter/flush step for one query against one staged candidate.
// All state (thresh_hi, cnt) is wave-uniform; branches are wave-uniform.
__device__ __forceinline__ void filter_step(float4 q, float4 c, unsigned idx32,
                                            unsigned& thresh_hi, int& cnt,
                                            ull& R, ull* buf, int lane) {
  float dot = __fadd_rn(__fadd_rn(__fmul_rn(q.x, c.x), __fmul_rn(q.y, c.y)),
                        __fmul_rn(q.z, c.z));
  float d2 = __fsub_rn(__fadd_rn(q.w, c.w), __fmul_rn(2.0f, dot));
  unsigned bits = __float_as_uint(d2);
  unsigned fk = bits ^ (0x80000000u | (unsigned)((int)bits >> 31));
  bool pred = fk <= thresh_hi;     // superset of exact u64 test; flush is exact
  ull mask = __ballot(pred);
  if (mask) {
    int pos = cnt + (int)__builtin_amdgcn_mbcnt_hi(
                        (unsigned)(mask >> 32),
                        __builtin_amdgcn_mbcnt_lo((unsigned)mask, 0u));
    if (pred) buf[pos] = ((ull)fk << 32) | idx32;
    cnt += __popcll(mask);
    if (cnt >= 64) {
      ull v = buf[lane];
      v = bitonic_sort64(v, lane);
      ull vr = __shfl(v, 63 - lane);
      R = minu64(R, vr);
      R = bitonic_merge64(R, lane);
      thresh_hi = (unsigned)__shfl((int)(unsigned)(R >> 32), 15);
      cnt -= 64;
      if (lane < cnt) {
        ull tmp = buf[64 + lane];
        buf[lane] = tmp;
      }
    }
  }
}

__device__ __forceinline__ ull final_flush(ull R, int cnt, ull* buf, int lane) {
  ull v = (lane < cnt) ? buf[lane] : ~0ull;
  v = bitonic_sort64(v, lane);
  ull vr = __shfl(v, 63 - lane);
  R = minu64(R, vr);
  return bitonic_merge64(R, lane);
}

// MEGA kernel v11: knn now processes 2 QUERIES PER WAVE — one ds_read_b128 of
// a candidate feeds both queries' filter steps, halving the dominant per-CU
// LDS-tile traffic (R8 showed the VALU slimming was null -> DS+VALU co-critical).
//   blocks [0,2048):    KNN, 8 queries/block (dispatched FIRST, long pole)
//   blocks [2048,4096): P/Q, 2 points/wave (backfills knn's ragged tail)
//   blocks [4096,4145): W1/W2/bias fold for mlp
__global__ __launch_bounds__(256) void mega_kernel(
    const float* __restrict__ xyz, const float* __restrict__ points,
    const float* __restrict__ w0, const float* __restrict__ b0, const float* __restrict__ g0,
    const float* __restrict__ be0, const float* __restrict__ rm0, const float* __restrict__ rv0,
    const float* __restrict__ w1, const float* __restrict__ b1, const float* __restrict__ g1,
    const float* __restrict__ be1, const float* __restrict__ rm1, const float* __restrict__ rv1,
    const float* __restrict__ w2, const float* __restrict__ b2, const float* __restrict__ g2,
    const float* __restrict__ be2, const float* __restrict__ rm2, const float* __restrict__ rv2,
    float* __restrict__ ws, int* __restrict__ knnOut) {
  __shared__ __align__(16) unsigned char smem[24576];  // knn: 16K tile + 8K buf; pq: 17.2K w0
  int blk = blockIdx.x;
  int tid = threadIdx.x;

  if (blk < 2048) {
    // ---------------- KNN: 2 queries/wave threshold-filter ----------------
    float4* tile = (float4*)smem;                 // [1024] candidate (x,y,z,sq)
    ull* bufb = (ull*)(smem + 16384);             // [4 waves][2 queries][128]
    int lane = tid & 63, w = tid >> 6;
    int b = blk >> 9;                             // 512 blocks per batch
    int n0 = ((blk & 511) << 3) + (w << 1);
    int n1 = n0 + 1;
    const float* xb = xyz + (size_t)b * NPT * 3;
    ull* buf0 = bufb + w * 256;
    ull* buf1 = buf0 + 128;

    float4 q0, q1;
    {
      const float* qp = xb + n0 * 3;
      float ax = qp[0], ay = qp[1], az = qp[2];
      float bx = qp[3], by = qp[4], bz = qp[5];
      q0 = make_float4(ax, ay, az,
          __fadd_rn(__fadd_rn(__fmul_rn(ax, ax), __fmul_rn(ay, ay)), __fmul_rn(az, az)));
      q1 = make_float4(bx, by, bz,
          __fadd_rn(__fadd_rn(__fmul_rn(bx, bx), __fmul_rn(by, by)), __fmul_rn(bz, bz)));
    }
    ull R0 = ~0ull, R1 = ~0ull;
    unsigned th0 = 0xFFFFFFFFu, th1 = 0xFFFFFFFFu;
    int cnt0 = 0, cnt1 = 0;
    const float4* r4 = (const float4*)xb;         // batch base, 16B-aligned

#pragma unroll 1
    for (int t = 0; t < 4; ++t) {
      __syncthreads();
      {
        // stage 1024 candidates from raw xyz: 3 coalesced float4 loads = 4 cands
        int fo = 768 * t + 3 * tid;
        float4 A = r4[fo], B = r4[fo + 1], C = r4[fo + 2];
        float xs[4] = {A.x, A.w, B.z, C.y};
        float ys[4] = {A.y, B.x, B.w, C.z};
        float zs[4] = {A.z, B.y, C.x, C.w};
#pragma unroll
        for (int j = 0; j < 4; ++j) {
          float sq = __fadd_rn(__fadd_rn(__fmul_rn(xs[j], xs[j]), __fmul_rn(ys[j], ys[j])),
                               __fmul_rn(zs[j], zs[j]));
          tile[4 * tid + j] = make_float4(xs[j], ys[j], zs[j], sq);
        }
      }
      __syncthreads();
#pragma unroll 1
      for (int i = 0; i < 16; ++i) {
        float4 c = tile[(i << 6) + lane];          // one read serves BOTH queries
        unsigned idx32 = (unsigned)((t << 10) + (i << 6) + lane);
        filter_step(q0, c, idx32, th0, cnt0, R0, buf0, lane);
        filter_step(q1, c, idx32, th1, cnt1, R1, buf1, lane);
      }
    }
    R0 = final_flush(R0, cnt0, buf0, lane);
    R1 = final_flush(R1, cnt1, buf1, lane);
    if (lane < KNN_K) {
      knnOut[(b * NPT + n0) * KNN_K + lane] = (int)(unsigned)(R0 & 0xFFFFFFFFull);
      knnOut[(b * NPT + n1) * KNN_K + lane] = (int)(unsigned)(R1 & 0xFFFFFFFFull);
    }
    return;
  }

  if (blk < 4096) {
    // ---------------- P/Q precompute: 2 points per wave ------------------
    float* wlds = (float*)smem;                   // [64*67] folded w0
    for (int j = tid; j < 4288; j += 256) {
      int r = j / 67;
      float s = g0[r] * rsqrtf(rv0[r] + EPSV);
      wlds[j] = __fmul_rn(w0[j], s);
    }
    __syncthreads();
    int oc = tid & 63;
    int base = (blk - 2048) * 8 + (tid >> 6);
    float s = g0[oc] * rsqrtf(rv0[oc] + EPSV);
    float b0f = (b0[oc] - rm0[oc]) * s + be0[oc];
    const float* wrow = wlds + oc * 67;           // stride-67 -> 2-way bank (free)
#pragma unroll 1
    for (int pt = 0; pt < 2; ++pt) {
      int i = base + pt * 4;
      float x = xyz[i * 3], y = xyz[i * 3 + 1], z = xyz[i * 3 + 2];
      float qacc = wrow[0] * x;
      qacc = fmaf(wrow[1], y, qacc);
      qacc = fmaf(wrow[2], z, qacc);
      float acc = b0f + qacc;
      const float* prow = points + (size_t)i * 64;
#pragma unroll 4
      for (int c = 0; c < 64; ++c) acc = fmaf(wrow[3 + c], prow[c], acc);
      ws[P_OFF + (size_t)i * 64 + oc] = acc;
      ws[Q_OFF + (size_t)i * 64 + oc] = qacc;
    }
    return;
  }

  // ---------------- weight fold for mlp (W1T/B1/W2T/B2) ------------------
  {
    int i = (blk - 4096) * 256 + tid + 4352;
    if (i < 8448) {
      int j = i - 4352; int oc = j & 63, ic = j >> 6;
      float s = g1[oc] * rsqrtf(rv1[oc] + EPSV);
      ws[i] = w1[oc * 64 + ic] * s;
    } else if (i < 8512) {
      int oc = i - 8448;
      float s = g1[oc] * rsqrtf(rv1[oc] + EPSV);
      ws[i] = (b1[oc] - rm1[oc]) * s + be1[oc];
    } else if (i < 16704) {
      int j = i - 8512; int ic = j >> 7, oc = j & 127;
      float s = g2[oc] * rsqrtf(rv2[oc] + EPSV);
      ws[i] = w2[oc * 64 + ic] * s;               // w2t [ic][oc]
    } else if (i < 16832) {
      int oc = i - 16704;
      float s = g2[oc] * rsqrtf(rv2[oc] + EPSV);
      ws[i] = (b2[oc] - rm2[oc]) * s + be2[oc];
    }
  }
}

// MLP v10 (kept byte-identical; ~82us, passed): block = 256 thr = 8 queries =
// 128 pairs. L1: 4p x 8oc; L2 single pass 8p x 8oc. W chunked via register
// preloads. LDS 48 KB -> 3 blocks/CU. Accumulation bias + ic 0..63 sequential.
__global__ __launch_bounds__(256, 3) void mlp_kernel(
    const float* __restrict__ wbuf, const int* __restrict__ knn,
    float* __restrict__ out) {
  __shared__ __align__(16) float Ash[64 * 128];   // 32 KB [ic][p]
  __shared__ __align__(16) float Wsh[32 * 128];   // 16 KB (W1 chunks use 1st 8 KB)
  int tid = threadIdx.x;
  int qblk = blockIdx.x << 3;                     // 8 flat queries per block

  const float4* w1g = (const float4*)(wbuf + W1T_OFF);   // [64][16 f4]
  const float4* w2g = (const float4*)(wbuf + W2T_OFF);   // [64][32 f4]
  float4* wl = (float4*)Wsh;

  // W2 chunk h (ic-half): entry e in [0,1024) f4 -> global row 32h+(e>>5), colf4 e&31
#define W2C(e, h) ((((h) << 5) + ((e) >> 5)) * 32 + ((e) & 31))

  // ---- preload W1a ----
  float4 s0 = w1g[tid];
  float4 s1 = w1g[256 + tid];
  float4 s2, s3;

  // ---- h0: pair p = tid&127, ic-half = tid>>7 ----
  {
    int p = tid & 127, half = tid >> 7;
    int q = qblk + (p >> 4);
    int k = p & 15;
    int src = knn[q * KNN_K + k];                 // coalesced across 128 threads
    int srow = (q & ~(NPT - 1)) + src;
    const float4* Pp = (const float4*)(wbuf + P_OFF + (size_t)srow * 64 + half * 32);
    const float4* Qp = (const float4*)(wbuf + Q_OFF + (size_t)q * 64 + half * 32);
#pragma unroll
    for (int j = 0; j < 8; ++j) {
      float4 pv = Pp[j];
      float4 qv = Qp[j];
      int ic = half * 32 + j * 4;
      Ash[(ic + 0) * 128 + p] = fmaxf(pv.x - qv.x, 0.0f);
      Ash[(ic + 1) * 128 + p] = fmaxf(pv.y - qv.y, 0.0f);
      Ash[(ic + 2) * 128 + p] = fmaxf(pv.z - qv.z, 0.0f);
      Ash[(ic + 3) * 128 + p] = fmaxf(pv.w - qv.w, 0.0f);
    }
  }
  // write W1a; preload W1b
  wl[tid] = s0; wl[256 + tid] = s1;
  s0 = w1g[512 + tid]; s1 = w1g[768 + tid];
  __syncthreads();                                 // S1: h0 + W1a visible

  int og = tid & 7, pg = tid >> 3;                 // L1: 32 pgrp x 8 ogrp
  const float* Arow = Ash + 4 * pg;
  const float* Wrow = Wsh + 8 * og;
  float acc[8][8];                                 // L1 uses [0..3][..]

#define GEMM32(R0)                                                        \
  _Pragma("unroll 8")                                                     \
  for (int ic = 0; ic < 32; ++ic) {                                       \
    float4 a0 = *(const float4*)(Arow + ((R0) + ic) * 128);               \
    float4 wv0 = *(const float4*)(Wrow + ic * 64);                        \
    float4 wv1 = *(const float4*)(Wrow + ic * 64 + 4);                    \
    float av[4] = {a0.x, a0.y, a0.z, a0.w};                               \
    float wv[8] = {wv0.x, wv0.y, wv0.z, wv0.w, wv1.x, wv1.y, wv1.z, wv1.w};\
    _Pragma("unroll")                                                     \
    for (int ii = 0; ii < 4; ++ii)                                        \
      _Pragma("unroll")                                                   \
      for (int jj = 0; jj < 8; ++jj) acc[ii][jj] = fmaf(av[ii], wv[jj], acc[ii][jj]); \
  }

  // ---- layer 1 ----
  {
    float4 b0v = *(const float4*)(wbuf + B1_OFF + 8 * og);
    float4 b1v = *(const float4*)(wbuf + B1_OFF + 8 * og + 4);
    float bj[8] = {b0v.x, b0v.y, b0v.z, b0v.w, b1v.x, b1v.y, b1v.z, b1v.w};
#pragma unroll
    for (int i = 0; i < 4; ++i)
#pragma unroll
      for (int j = 0; j < 8; ++j) acc[i][j] = bj[j];
  }
  GEMM32(0)                                        // W1a: ic 0..31
  __syncthreads();                                 // S2: W1a reads done
  wl[tid] = s0; wl[256 + tid] = s1;                // write W1b
  s0 = w2g[W2C(tid, 0)];       s1 = w2g[W2C(tid + 256, 0)];
  s2 = w2g[W2C(tid + 512, 0)]; s3 = w2g[W2C(tid + 768, 0)];
  __syncthreads();                                 // S3: W1b visible
  GEMM32(32)                                       // W1b: ic 32..63
  __syncthreads();                                 // S4: all h0 + W1b reads done

  // h1 -> A[oc][p]
#pragma unroll
  for (int j = 0; j < 8; ++j) {
    int oc = 8 * og + j;
    *(float4*)(Ash + oc * 128 + 4 * pg) =
        make_float4(fmaxf(acc[0][j], 0.0f), fmaxf(acc[1][j], 0.0f),
                    fmaxf(acc[2][j], 0.0f), fmaxf(acc[3][j], 0.0f));
  }
  // write W2 chunk0; preload chunk1
  wl[tid] = s0; wl[256 + tid] = s1; wl[512 + tid] = s2; wl[768 + tid] = s3;
  s0 = w2g[W2C(tid, 1)];       s1 = w2g[W2C(tid + 256, 1)];
  s2 = w2g[W2C(tid + 512, 1)]; s3 = w2g[W2C(tid + 768, 1)];
  __syncthreads();                                 // S5: h1 + W2c0 visible

  // ---- layer 2: single pass, 128 oc, 8p x 8oc per thread ----
  int og2 = tid & 15, pg2 = tid >> 4;              // 16 pgrp x 16 ogrp
  const float* Arow2 = Ash + 8 * pg2;
  const float* Wrow2 = Wsh + 8 * og2;

#define GEMM32L2(R0)                                                      \
  _Pragma("unroll 4")                                                     \
  for (int ic = 0; ic < 32; ++ic) {                                       \
    float4 a0 = *(const float4*)(Arow2 + ((R0) + ic) * 128);              \
    float4 a1 = *(const float4*)(Arow2 + ((R0) + ic) * 128 + 4);          \
    float4 wv0 = *(const float4*)(Wrow2 + ic * 128);                      \
    float4 wv1 = *(const float4*)(Wrow2 + ic * 128 + 4);                  \
    float av[8] = {a0.x, a0.y, a0.z, a0.w, a1.x, a1.y, a1.z, a1.w};       \
    float wv[8] = {wv0.x, wv0.y, wv0.z, wv0.w, wv1.x, wv1.y, wv1.z, wv1.w};\
    _Pragma("unroll")                                                     \
    for (int ii = 0; ii < 8; ++ii)                                        \
      _Pragma("unroll")                                                   \
      for (int jj = 0; jj < 8; ++jj) acc[ii][jj] = fmaf(av[ii], wv[jj], acc[ii][jj]); \
  }

  {
    float4 b0v = *(const float4*)(wbuf + B2_OFF + 8 * og2);
    float4 b1v = *(const float4*)(wbuf + B2_OFF + 8 * og2 + 4);
    float bj[8] = {b0v.x, b0v.y, b0v.z, b0v.w, b1v.x, b1v.y, b1v.z, b1v.w};
#pragma unroll
    for (int i = 0; i < 8; ++i)
#pragma unroll
      for (int j = 0; j < 8; ++j) acc[i][j] = bj[j];
  }
  GEMM32L2(0)                                      // W2c0: ic 0..31
  __syncthreads();                                 // S6: W2c0 reads done
  wl[tid] = s0; wl[256 + tid] = s1; wl[512 + tid] = s2; wl[768 + tid] = s3;
  __syncthreads();                                 // S7: W2c1 visible
  GEMM32L2(32)                                     // W2c1: ic 32..63

  // relu + max over 8 in-thread pairs (k 0..7 or 8..15), then pg2^1 partner
  {
    int qout = qblk + (pg2 >> 1);
    float* obase = out + (size_t)qout * 128 + 8 * og2;
    float m[8];
#pragma unroll
    for (int j = 0; j < 8; ++j) {
      float v = fmaxf(fmaxf(fmaxf(acc[0][j], acc[1][j]), fmaxf(acc[2][j], acc[3][j])),
                      fmaxf(fmaxf(acc[4][j], acc[5][j]), fmaxf(acc[6][j], acc[7][j])));
      v = fmaxf(v, 0.0f);
      m[j] = fmaxf(v, __shfl_xor(v, 16));          // pg2 bit 0 (tid bit 4)
    }
    if ((pg2 & 1) == 0) {
      *(float4*)(obase)     = make_float4(m[0], m[1], m[2], m[3]);
      *(float4*)(obase + 4) = make_float4(m[4], m[5], m[6], m[7]);
    }
  }
#undef GEMM32
#undef GEMM32L2
#undef W2C
}

extern "C" void kernel_launch(void* const* d_in, const int* in_sizes, int n_in,
                              void* d_out, int out_size, void* d_ws, size_t ws_size,
                              hipStream_t stream) {
  const float* xyz    = (const float*)d_in[0];
  const float* points = (const float*)d_in[1];
  float* wsF = (float*)d_ws;
  int* idxBuf = (int*)(wsF + IDX_OFF);

  mega_kernel<<<4145, 256, 0, stream>>>(
      xyz, points,
      (const float*)d_in[2],  (const float*)d_in[3],  (const float*)d_in[4],
      (const float*)d_in[5],  (const float*)d_in[6],  (const float*)d_in[7],
      (const float*)d_in[8],  (const float*)d_in[9],  (const float*)d_in[10],
      (const float*)d_in[11], (const float*)d_in[12], (const float*)d_in[13],
      (const float*)d_in[14], (const float*)d_in[15], (const float*)d_in[16],
      (const float*)d_in[17], (const float*)d_in[18], (const float*)d_in[19],
      wsF, idxBuf);
  mlp_kernel<<<2048, 256, 0, stream>>>(wsF, idxBuf, (float*)d_out);
}

// Round 10
// 241.045 us; speedup vs baseline: 1.0813x; 1.0672x over previous
//
#include <hip/hip_runtime.h>

#define NPT   4096
#define KNN_K 16
#define EPSV  1e-5f

// ---- ws float layout ----
#define W1T_OFF 4352               // [64][64]  (ic-major)
#define B1_OFF  8448               // [64]
#define W2T_OFF 8512               // [64][128] (ic-major)
#define B2_OFF  16704              // [128]
#define IDX_OFF 16832              // int[4*4096*16]
#define P_OFF   344512             // float[16384][64]  P = W0p*pts + W0x*xyz + b0
#define Q_OFF   1393088            // float[16384][64]  Q = W0x*xyz

typedef unsigned long long ull;

__device__ __forceinline__ ull minu64(ull a, ull b) { return a < b ? a : b; }
__device__ __forceinline__ ull maxu64(ull a, ull b) { return a > b ? a : b; }

__device__ __forceinline__ ull bitonic_sort64(ull v, int lane) {
#pragma unroll
  for (int k = 2; k <= 64; k <<= 1) {
#pragma unroll
    for (int j = k >> 1; j > 0; j >>= 1) {
      ull o = __shfl_xor(v, j);
      bool lower = (lane & j) == 0;
      bool up = (lane & k) == 0;
      v = (lower == up) ? minu64(v, o) : maxu64(v, o);
    }
  }
  return v;
}

__device__ __forceinline__ ull bitonic_merge64(ull v, int lane) {
#pragma unroll
  for (int j = 32; j > 0; j >>= 1) {
    ull o = __shfl_xor(v, j);
    v = ((lane & j) == 0) ? minu64(v, o) : maxu64(v, o);
  }
  return v;
}

// One filter/flush step for one query against one lane-resident candidate.
// All state (thresh_hi, cnt) is wave-uniform; branches are wave-uniform.
__device__ __forceinline__ void filter_step(float4 q, float4 c, unsigned idx32,
                                            unsigned& thresh_hi, int& cnt,
                                            ull& R, ull* buf, int lane) {
  float dot = __fadd_rn(__fadd_rn(__fmul_rn(q.x, c.x), __fmul_rn(q.y, c.y)),
                        __fmul_rn(q.z, c.z));
  float d2 = __fsub_rn(__fadd_rn(q.w, c.w), __fmul_rn(2.0f, dot));
  unsigned bits = __float_as_uint(d2);
  unsigned fk = bits ^ (0x80000000u | (unsigned)((int)bits >> 31));
  bool pred = fk <= thresh_hi;     // superset of exact u64 test; flush is exact
  ull mask = __ballot(pred);
  if (mask) {
    int pos = cnt + (int)__builtin_amdgcn_mbcnt_hi(
                        (unsigned)(mask >> 32),
                        __builtin_amdgcn_mbcnt_lo((unsigned)mask, 0u));
    if (pred) buf[pos] = ((ull)fk << 32) | idx32;
    cnt += __popcll(mask);
    if (cnt >= 64) {
      ull v = buf[lane];
      v = bitonic_sort64(v, lane);
      ull vr = __shfl(v, 63 - lane);
      R = minu64(R, vr);
      R = bitonic_merge64(R, lane);
      thresh_hi = (unsigned)__shfl((int)(unsigned)(R >> 32), 15);
      cnt -= 64;
      if (lane < cnt) {
        ull tmp = buf[64 + lane];
        buf[lane] = tmp;
      }
    }
  }
}

__device__ __forceinline__ ull final_flush(ull R, int cnt, ull* buf, int lane) {
  ull v = (lane < cnt) ? buf[lane] : ~0ull;
  v = bitonic_sort64(v, lane);
  ull vr = __shfl(v, 63 - lane);
  R = minu64(R, vr);
  return bitonic_merge64(R, lane);
}

// MEGA kernel v12: knn goes REGISTER-DIRECT — lane l holds candidate g+l,
// loaded straight from global (L1/L2-resident, xyz=48KB/batch), sq recomputed
// with the identical rounding sequence. Removes the LDS tile, its 64
// ds_read_b128/wave, the staging writes, and ALL __syncthreads in the knn
// path (R9: tile halving gave only -5.5us and cost occupancy; barriers+DS+
// occupancy were the co-limiters). LDS now only the flush buffers (8KB).
// 1-deep manual pipeline hides L2 latency; 2 queries/wave amortize each
// candidate across two filter steps.
//   blocks [0,2048):    KNN, 8 queries/block (dispatched FIRST, long pole)
//   blocks [2048,4096): P/Q, 2 points/wave (backfills knn's ragged tail)
//   blocks [4096,4145): W1/W2/bias fold for mlp
__global__ __launch_bounds__(256) void mega_kernel(
    const float* __restrict__ xyz, const float* __restrict__ points,
    const float* __restrict__ w0, const float* __restrict__ b0, const float* __restrict__ g0,
    const float* __restrict__ be0, const float* __restrict__ rm0, const float* __restrict__ rv0,
    const float* __restrict__ w1, const float* __restrict__ b1, const float* __restrict__ g1,
    const float* __restrict__ be1, const float* __restrict__ rm1, const float* __restrict__ rv1,
    const float* __restrict__ w2, const float* __restrict__ b2, const float* __restrict__ g2,
    const float* __restrict__ be2, const float* __restrict__ rm2, const float* __restrict__ rv2,
    float* __restrict__ ws, int* __restrict__ knnOut) {
  __shared__ __align__(16) unsigned char smem[20480];  // knn: 8K flush bufs; pq: 17.2K w0
  int blk = blockIdx.x;
  int tid = threadIdx.x;

  if (blk < 2048) {
    // ---------------- KNN: 2 queries/wave, register-direct candidates -----
    ull* bufb = (ull*)smem;                       // [4 waves][2 queries][128]
    int lane = tid & 63, w = tid >> 6;
    int b = blk >> 9;                             // 512 blocks per batch
    int n0 = ((blk & 511) << 3) + (w << 1);
    int n1 = n0 + 1;
    const float* xb = xyz + (size_t)b * NPT * 3;
    ull* buf0 = bufb + w * 256;
    ull* buf1 = buf0 + 128;

    float4 q0, q1;
    {
      const float* qp = xb + n0 * 3;
      float ax = qp[0], ay = qp[1], az = qp[2];
      float bx = qp[3], by = qp[4], bz = qp[5];
      q0 = make_float4(ax, ay, az,
          __fadd_rn(__fadd_rn(__fmul_rn(ax, ax), __fmul_rn(ay, ay)), __fmul_rn(az, az)));
      q1 = make_float4(bx, by, bz,
          __fadd_rn(__fadd_rn(__fmul_rn(bx, bx), __fmul_rn(by, by)), __fmul_rn(bz, bz)));
    }
    ull R0 = ~0ull, R1 = ~0ull;
    unsigned th0 = 0xFFFFFFFFu, th1 = 0xFFFFFFFFu;
    int cnt0 = 0, cnt1 = 0;

    // iter-0 preload (lane-resident candidate)
    float cx = xb[3 * lane], cy = xb[3 * lane + 1], cz = xb[3 * lane + 2];
#pragma unroll 1
    for (int g = 0; g < NPT; g += 64) {
      // prefetch next group (clamped on last iter; values unused)
      int ni = 3 * ((g + 64 + lane) & (NPT - 1));
      float nx = xb[ni], ny = xb[ni + 1], nz = xb[ni + 2];
      float csq = __fadd_rn(__fadd_rn(__fmul_rn(cx, cx), __fmul_rn(cy, cy)),
                            __fmul_rn(cz, cz));
      float4 c = make_float4(cx, cy, cz, csq);
      unsigned idx32 = (unsigned)(g + lane);
      filter_step(q0, c, idx32, th0, cnt0, R0, buf0, lane);
      filter_step(q1, c, idx32, th1, cnt1, R1, buf1, lane);
      cx = nx; cy = ny; cz = nz;
    }
    R0 = final_flush(R0, cnt0, buf0, lane);
    R1 = final_flush(R1, cnt1, buf1, lane);
    if (lane < KNN_K) {
      knnOut[(b * NPT + n0) * KNN_K + lane] = (int)(unsigned)(R0 & 0xFFFFFFFFull);
      knnOut[(b * NPT + n1) * KNN_K + lane] = (int)(unsigned)(R1 & 0xFFFFFFFFull);
    }
    return;
  }

  if (blk < 4096) {
    // ---------------- P/Q precompute: 2 points per wave ------------------
    float* wlds = (float*)smem;                   // [64*67] folded w0
    for (int j = tid; j < 4288; j += 256) {
      int r = j / 67;
      float s = g0[r] * rsqrtf(rv0[r] + EPSV);
      wlds[j] = __fmul_rn(w0[j], s);
    }
    __syncthreads();
    int oc = tid & 63;
    int base = (blk - 2048) * 8 + (tid >> 6);
    float s = g0[oc] * rsqrtf(rv0[oc] + EPSV);
    float b0f = (b0[oc] - rm0[oc]) * s + be0[oc];
    const float* wrow = wlds + oc * 67;           // stride-67 -> 2-way bank (free)
#pragma unroll 1
    for (int pt = 0; pt < 2; ++pt) {
      int i = base + pt * 4;
      float x = xyz[i * 3], y = xyz[i * 3 + 1], z = xyz[i * 3 + 2];
      float qacc = wrow[0] * x;
      qacc = fmaf(wrow[1], y, qacc);
      qacc = fmaf(wrow[2], z, qacc);
      float acc = b0f + qacc;
      const float* prow = points + (size_t)i * 64;
#pragma unroll 4
      for (int c = 0; c < 64; ++c) acc = fmaf(wrow[3 + c], prow[c], acc);
      ws[P_OFF + (size_t)i * 64 + oc] = acc;
      ws[Q_OFF + (size_t)i * 64 + oc] = qacc;
    }
    return;
  }

  // ---------------- weight fold for mlp (W1T/B1/W2T/B2) ------------------
  {
    int i = (blk - 4096) * 256 + tid + 4352;
    if (i < 8448) {
      int j = i - 4352; int oc = j & 63, ic = j >> 6;
      float s = g1[oc] * rsqrtf(rv1[oc] + EPSV);
      ws[i] = w1[oc * 64 + ic] * s;
    } else if (i < 8512) {
      int oc = i - 8448;
      float s = g1[oc] * rsqrtf(rv1[oc] + EPSV);
      ws[i] = (b1[oc] - rm1[oc]) * s + be1[oc];
    } else if (i < 16704) {
      int j = i - 8512; int ic = j >> 7, oc = j & 127;
      float s = g2[oc] * rsqrtf(rv2[oc] + EPSV);
      ws[i] = w2[oc * 64 + ic] * s;               // w2t [ic][oc]
    } else if (i < 16832) {
      int oc = i - 16704;
      float s = g2[oc] * rsqrtf(rv2[oc] + EPSV);
      ws[i] = (b2[oc] - rm2[oc]) * s + be2[oc];
    }
  }
}

// MLP v10 (kept byte-identical; ~84us, passed): block = 256 thr = 8 queries =
// 128 pairs. L1: 4p x 8oc; L2 single pass 8p x 8oc. W chunked via register
// preloads. LDS 48 KB -> 3 blocks/CU. Accumulation bias + ic 0..63 sequential.
__global__ __launch_bounds__(256, 3) void mlp_kernel(
    const float* __restrict__ wbuf, const int* __restrict__ knn,
    float* __restrict__ out) {
  __shared__ __align__(16) float Ash[64 * 128];   // 32 KB [ic][p]
  __shared__ __align__(16) float Wsh[32 * 128];   // 16 KB (W1 chunks use 1st 8 KB)
  int tid = threadIdx.x;
  int qblk = blockIdx.x << 3;                     // 8 flat queries per block

  const float4* w1g = (const float4*)(wbuf + W1T_OFF);   // [64][16 f4]
  const float4* w2g = (const float4*)(wbuf + W2T_OFF);   // [64][32 f4]
  float4* wl = (float4*)Wsh;

  // W2 chunk h (ic-half): entry e in [0,1024) f4 -> global row 32h+(e>>5), colf4 e&31
#define W2C(e, h) ((((h) << 5) + ((e) >> 5)) * 32 + ((e) & 31))

  // ---- preload W1a ----
  float4 s0 = w1g[tid];
  float4 s1 = w1g[256 + tid];
  float4 s2, s3;

  // ---- h0: pair p = tid&127, ic-half = tid>>7 ----
  {
    int p = tid & 127, half = tid >> 7;
    int q = qblk + (p >> 4);
    int k = p & 15;
    int src = knn[q * KNN_K + k];                 // coalesced across 128 threads
    int srow = (q & ~(NPT - 1)) + src;
    const float4* Pp = (const float4*)(wbuf + P_OFF + (size_t)srow * 64 + half * 32);
    const float4* Qp = (const float4*)(wbuf + Q_OFF + (size_t)q * 64 + half * 32);
#pragma unroll
    for (int j = 0; j < 8; ++j) {
      float4 pv = Pp[j];
      float4 qv = Qp[j];
      int ic = half * 32 + j * 4;
      Ash[(ic + 0) * 128 + p] = fmaxf(pv.x - qv.x, 0.0f);
      Ash[(ic + 1) * 128 + p] = fmaxf(pv.y - qv.y, 0.0f);
      Ash[(ic + 2) * 128 + p] = fmaxf(pv.z - qv.z, 0.0f);
      Ash[(ic + 3) * 128 + p] = fmaxf(pv.w - qv.w, 0.0f);
    }
  }
  // write W1a; preload W1b
  wl[tid] = s0; wl[256 + tid] = s1;
  s0 = w1g[512 + tid]; s1 = w1g[768 + tid];
  __syncthreads();                                 // S1: h0 + W1a visible

  int og = tid & 7, pg = tid >> 3;                 // L1: 32 pgrp x 8 ogrp
  const float* Arow = Ash + 4 * pg;
  const float* Wrow = Wsh + 8 * og;
  float acc[8][8];                                 // L1 uses [0..3][..]

#define GEMM32(R0)                                                        \
  _Pragma("unroll 8")                                                     \
  for (int ic = 0; ic < 32; ++ic) {                                       \
    float4 a0 = *(const float4*)(Arow + ((R0) + ic) * 128);               \
    float4 wv0 = *(const float4*)(Wrow + ic * 64);                        \
    float4 wv1 = *(const float4*)(Wrow + ic * 64 + 4);                    \
    float av[4] = {a0.x, a0.y, a0.z, a0.w};                               \
    float wv[8] = {wv0.x, wv0.y, wv0.z, wv0.w, wv1.x, wv1.y, wv1.z, wv1.w};\
    _Pragma("unroll")                                                     \
    for (int ii = 0; ii < 4; ++ii)                                        \
      _Pragma("unroll")                                                   \
      for (int jj = 0; jj < 8; ++jj) acc[ii][jj] = fmaf(av[ii], wv[jj], acc[ii][jj]); \
  }

  // ---- layer 1 ----
  {
    float4 b0v = *(const float4*)(wbuf + B1_OFF + 8 * og);
    float4 b1v = *(const float4*)(wbuf + B1_OFF + 8 * og + 4);
    float bj[8] = {b0v.x, b0v.y, b0v.z, b0v.w, b1v.x, b1v.y, b1v.z, b1v.w};
#pragma unroll
    for (int i = 0; i < 4; ++i)
#pragma unroll
      for (int j = 0; j < 8; ++j) acc[i][j] = bj[j];
  }
  GEMM32(0)                                        // W1a: ic 0..31
  __syncthreads();                                 // S2: W1a reads done
  wl[tid] = s0; wl[256 + tid] = s1;                // write W1b
  s0 = w2g[W2C(tid, 0)];       s1 = w2g[W2C(tid + 256, 0)];
  s2 = w2g[W2C(tid + 512, 0)]; s3 = w2g[W2C(tid + 768, 0)];
  __syncthreads();                                 // S3: W1b visible
  GEMM32(32)                                       // W1b: ic 32..63
  __syncthreads();                                 // S4: all h0 + W1b reads done

  // h1 -> A[oc][p]
#pragma unroll
  for (int j = 0; j < 8; ++j) {
    int oc = 8 * og + j;
    *(float4*)(Ash + oc * 128 + 4 * pg) =
        make_float4(fmaxf(acc[0][j], 0.0f), fmaxf(acc[1][j], 0.0f),
                    fmaxf(acc[2][j], 0.0f), fmaxf(acc[3][j], 0.0f));
  }
  // write W2 chunk0; preload chunk1
  wl[tid] = s0; wl[256 + tid] = s1; wl[512 + tid] = s2; wl[768 + tid] = s3;
  s0 = w2g[W2C(tid, 1)];       s1 = w2g[W2C(tid + 256, 1)];
  s2 = w2g[W2C(tid + 512, 1)]; s3 = w2g[W2C(tid + 768, 1)];
  __syncthreads();                                 // S5: h1 + W2c0 visible

  // ---- layer 2: single pass, 128 oc, 8p x 8oc per thread ----
  int og2 = tid & 15, pg2 = tid >> 4;              // 16 pgrp x 16 ogrp
  const float* Arow2 = Ash + 8 * pg2;
  const float* Wrow2 = Wsh + 8 * og2;

#define GEMM32L2(R0)                                                      \
  _Pragma("unroll 4")                                                     \
  for (int ic = 0; ic < 32; ++ic) {                                       \
    float4 a0 = *(const float4*)(Arow2 + ((R0) + ic) * 128);              \
    float4 a1 = *(const float4*)(Arow2 + ((R0) + ic) * 128 + 4);          \
    float4 wv0 = *(const float4*)(Wrow2 + ic * 128);                      \
    float4 wv1 = *(const float4*)(Wrow2 + ic * 128 + 4);                  \
    float av[8] = {a0.x, a0.y, a0.z, a0.w, a1.x, a1.y, a1.z, a1.w};       \
    float wv[8] = {wv0.x, wv0.y, wv0.z, wv0.w, wv1.x, wv1.y, wv1.z, wv1.w};\
    _Pragma("unroll")                                                     \
    for (int ii = 0; ii < 8; ++ii)                                        \
      _Pragma("unroll")                                                   \
      for (int jj = 0; jj < 8; ++jj) acc[ii][jj] = fmaf(av[ii], wv[jj], acc[ii][jj]); \
  }

  {
    float4 b0v = *(const float4*)(wbuf + B2_OFF + 8 * og2);
    float4 b1v = *(const float4*)(wbuf + B2_OFF + 8 * og2 + 4);
    float bj[8] = {b0v.x, b0v.y, b0v.z, b0v.w, b1v.x, b1v.y, b1v.z, b1v.w};
#pragma unroll
    for (int i = 0; i < 8; ++i)
#pragma unroll
      for (int j = 0; j < 8; ++j) acc[i][j] = bj[j];
  }
  GEMM32L2(0)                                      // W2c0: ic 0..31
  __syncthreads();                                 // S6: W2c0 reads done
  wl[tid] = s0; wl[256 + tid] = s1; wl[512 + tid] = s2; wl[768 + tid] = s3;
  __syncthreads();                                 // S7: W2c1 visible
  GEMM32L2(32)                                     // W2c1: ic 32..63

  // relu + max over 8 in-thread pairs (k 0..7 or 8..15), then pg2^1 partner
  {
    int qout = qblk + (pg2 >> 1);
    float* obase = out + (size_t)qout * 128 + 8 * og2;
    float m[8];
#pragma unroll
    for (int j = 0; j < 8; ++j) {
      float v = fmaxf(fmaxf(fmaxf(acc[0][j], acc[1][j]), fmaxf(acc[2][j], acc[3][j])),
                      fmaxf(fmaxf(acc[4][j], acc[5][j]), fmaxf(acc[6][j], acc[7][j])));
      v = fmaxf(v, 0.0f);
      m[j] = fmaxf(v, __shfl_xor(v, 16));          // pg2 bit 0 (tid bit 4)
    }
    if ((pg2 & 1) == 0) {
      *(float4*)(obase)     = make_float4(m[0], m[1], m[2], m[3]);
      *(float4*)(obase + 4) = make_float4(m[4], m[5], m[6], m[7]);
    }
  }
#undef GEMM32
#undef GEMM32L2
#undef W2C
}

extern "C" void kernel_launch(void* const* d_in, const int* in_sizes, int n_in,
                              void* d_out, int out_size, void* d_ws, size_t ws_size,
                              hipStream_t stream) {
  const float* xyz    = (const float*)d_in[0];
  const float* points = (const float*)d_in[1];
  float* wsF = (float*)d_ws;
  int* idxBuf = (int*)(wsF + IDX_OFF);

  mega_kernel<<<4145, 256, 0, stream>>>(
      xyz, points,
      (const float*)d_in[2],  (const float*)d_in[3],  (const float*)d_in[4],
      (const float*)d_in[5],  (const float*)d_in[6],  (const float*)d_in[7],
      (const float*)d_in[8],  (const float*)d_in[9],  (const float*)d_in[10],
      (const float*)d_in[11], (const float*)d_in[12], (const float*)d_in[13],
      (const float*)d_in[14], (const float*)d_in[15], (const float*)d_in[16],
      (const float*)d_in[17], (const float*)d_in[18], (const float*)d_in[19],
      wsF, idxBuf);
  mlp_kernel<<<2048, 256, 0, stream>>>(wsF, idxBuf, (float*)d_out);
}

// Round 11
// 238.908 us; speedup vs baseline: 1.0910x; 1.0089x over previous
//
#include <hip/hip_runtime.h>

#define NPT   4096
#define KNN_K 16
#define EPSV  1e-5f

// ---- ws float layout ----
#define W1T_OFF 4352               // [64][64]  (ic-major)
#define B1_OFF  8448               // [64]
#define W2T_OFF 8512               // [64][128] (ic-major)
#define B2_OFF  16704              // [128]
#define IDX_OFF 16832              // int[4*4096*16]
#define P_OFF   344512             // float[16384][64]  P = W0p*pts + W0x*xyz + b0
#define Q_OFF   1393088            // float[16384][64]  Q = W0x*xyz

typedef unsigned long long ull;

__device__ __forceinline__ ull minu64(ull a, ull b) { return a < b ? a : b; }
__device__ __forceinline__ ull maxu64(ull a, ull b) { return a > b ? a : b; }

__device__ __forceinline__ ull bitonic_sort64(ull v, int lane) {
#pragma unroll
  for (int k = 2; k <= 64; k <<= 1) {
#pragma unroll
    for (int j = k >> 1; j > 0; j >>= 1) {
      ull o = __shfl_xor(v, j);
      bool lower = (lane & j) == 0;
      bool up = (lane & k) == 0;
      v = (lower == up) ? minu64(v, o) : maxu64(v, o);
    }
  }
  return v;
}

__device__ __forceinline__ ull bitonic_merge64(ull v, int lane) {
#pragma unroll
  for (int j = 32; j > 0; j >>= 1) {
    ull o = __shfl_xor(v, j);
    v = ((lane & j) == 0) ? minu64(v, o) : maxu64(v, o);
  }
  return v;
}

// One filter/flush step for one query against one lane-resident candidate.
// All state (thresh_hi, cnt) is wave-uniform; branches are wave-uniform.
__device__ __forceinline__ void filter_step(float4 q, float4 c, unsigned idx32,
                                            unsigned& thresh_hi, int& cnt,
                                            ull& R, ull* buf, int lane) {
  float dot = __fadd_rn(__fadd_rn(__fmul_rn(q.x, c.x), __fmul_rn(q.y, c.y)),
                        __fmul_rn(q.z, c.z));
  float d2 = __fsub_rn(__fadd_rn(q.w, c.w), __fmul_rn(2.0f, dot));
  unsigned bits = __float_as_uint(d2);
  unsigned fk = bits ^ (0x80000000u | (unsigned)((int)bits >> 31));
  bool pred = fk <= thresh_hi;     // superset of exact u64 test; flush is exact
  ull mask = __ballot(pred);
  if (mask) {
    int pos = cnt + (int)__builtin_amdgcn_mbcnt_hi(
                        (unsigned)(mask >> 32),
                        __builtin_amdgcn_mbcnt_lo((unsigned)mask, 0u));
    if (pred) buf[pos] = ((ull)fk << 32) | idx32;
    cnt += __popcll(mask);
    if (cnt >= 64) {
      ull v = buf[lane];
      v = bitonic_sort64(v, lane);
      ull vr = __shfl(v, 63 - lane);
      R = minu64(R, vr);
      R = bitonic_merge64(R, lane);
      thresh_hi = (unsigned)__shfl((int)(unsigned)(R >> 32), 15);
      cnt -= 64;
      if (lane < cnt) {
        ull tmp = buf[64 + lane];
        buf[lane] = tmp;
      }
    }
  }
}

__device__ __forceinline__ ull final_flush(ull R, int cnt, ull* buf, int lane) {
  ull v = (lane < cnt) ? buf[lane] : ~0ull;
  v = bitonic_sort64(v, lane);
  ull vr = __shfl(v, 63 - lane);
  R = minu64(R, vr);
  return bitonic_merge64(R, lane);
}

// MEGA kernel v12 (kept byte-identical; mega ~76us measured-by-subtraction):
// knn register-direct, 2 queries/wave, no barriers in knn path.
//   blocks [0,2048):    KNN, 8 queries/block (dispatched FIRST, long pole)
//   blocks [2048,4096): P/Q, 2 points/wave (backfills knn's ragged tail)
//   blocks [4096,4145): W1/W2/bias fold for mlp
__global__ __launch_bounds__(256) void mega_kernel(
    const float* __restrict__ xyz, const float* __restrict__ points,
    const float* __restrict__ w0, const float* __restrict__ b0, const float* __restrict__ g0,
    const float* __restrict__ be0, const float* __restrict__ rm0, const float* __restrict__ rv0,
    const float* __restrict__ w1, const float* __restrict__ b1, const float* __restrict__ g1,
    const float* __restrict__ be1, const float* __restrict__ rm1, const float* __restrict__ rv1,
    const float* __restrict__ w2, const float* __restrict__ b2, const float* __restrict__ g2,
    const float* __restrict__ be2, const float* __restrict__ rm2, const float* __restrict__ rv2,
    float* __restrict__ ws, int* __restrict__ knnOut) {
  __shared__ __align__(16) unsigned char smem[20480];  // knn: 8K flush bufs; pq: 17.2K w0
  int blk = blockIdx.x;
  int tid = threadIdx.x;

  if (blk < 2048) {
    // ---------------- KNN: 2 queries/wave, register-direct candidates -----
    ull* bufb = (ull*)smem;                       // [4 waves][2 queries][128]
    int lane = tid & 63, w = tid >> 6;
    int b = blk >> 9;                             // 512 blocks per batch
    int n0 = ((blk & 511) << 3) + (w << 1);
    int n1 = n0 + 1;
    const float* xb = xyz + (size_t)b * NPT * 3;
    ull* buf0 = bufb + w * 256;
    ull* buf1 = buf0 + 128;

    float4 q0, q1;
    {
      const float* qp = xb + n0 * 3;
      float ax = qp[0], ay = qp[1], az = qp[2];
      float bx = qp[3], by = qp[4], bz = qp[5];
      q0 = make_float4(ax, ay, az,
          __fadd_rn(__fadd_rn(__fmul_rn(ax, ax), __fmul_rn(ay, ay)), __fmul_rn(az, az)));
      q1 = make_float4(bx, by, bz,
          __fadd_rn(__fadd_rn(__fmul_rn(bx, bx), __fmul_rn(by, by)), __fmul_rn(bz, bz)));
    }
    ull R0 = ~0ull, R1 = ~0ull;
    unsigned th0 = 0xFFFFFFFFu, th1 = 0xFFFFFFFFu;
    int cnt0 = 0, cnt1 = 0;

    // iter-0 preload (lane-resident candidate)
    float cx = xb[3 * lane], cy = xb[3 * lane + 1], cz = xb[3 * lane + 2];
#pragma unroll 1
    for (int g = 0; g < NPT; g += 64) {
      // prefetch next group (clamped on last iter; values unused)
      int ni = 3 * ((g + 64 + lane) & (NPT - 1));
      float nx = xb[ni], ny = xb[ni + 1], nz = xb[ni + 2];
      float csq = __fadd_rn(__fadd_rn(__fmul_rn(cx, cx), __fmul_rn(cy, cy)),
                            __fmul_rn(cz, cz));
      float4 c = make_float4(cx, cy, cz, csq);
      unsigned idx32 = (unsigned)(g + lane);
      filter_step(q0, c, idx32, th0, cnt0, R0, buf0, lane);
      filter_step(q1, c, idx32, th1, cnt1, R1, buf1, lane);
      cx = nx; cy = ny; cz = nz;
    }
    R0 = final_flush(R0, cnt0, buf0, lane);
    R1 = final_flush(R1, cnt1, buf1, lane);
    if (lane < KNN_K) {
      knnOut[(b * NPT + n0) * KNN_K + lane] = (int)(unsigned)(R0 & 0xFFFFFFFFull);
      knnOut[(b * NPT + n1) * KNN_K + lane] = (int)(unsigned)(R1 & 0xFFFFFFFFull);
    }
    return;
  }

  if (blk < 4096) {
    // ---------------- P/Q precompute: 2 points per wave ------------------
    float* wlds = (float*)smem;                   // [64*67] folded w0
    for (int j = tid; j < 4288; j += 256) {
      int r = j / 67;
      float s = g0[r] * rsqrtf(rv0[r] + EPSV);
      wlds[j] = __fmul_rn(w0[j], s);
    }
    __syncthreads();
    int oc = tid & 63;
    int base = (blk - 2048) * 8 + (tid >> 6);
    float s = g0[oc] * rsqrtf(rv0[oc] + EPSV);
    float b0f = (b0[oc] - rm0[oc]) * s + be0[oc];
    const float* wrow = wlds + oc * 67;           // stride-67 -> 2-way bank (free)
#pragma unroll 1
    for (int pt = 0; pt < 2; ++pt) {
      int i = base + pt * 4;
      float x = xyz[i * 3], y = xyz[i * 3 + 1], z = xyz[i * 3 + 2];
      float qacc = wrow[0] * x;
      qacc = fmaf(wrow[1], y, qacc);
      qacc = fmaf(wrow[2], z, qacc);
      float acc = b0f + qacc;
      const float* prow = points + (size_t)i * 64;
#pragma unroll 4
      for (int c = 0; c < 64; ++c) acc = fmaf(wrow[3 + c], prow[c], acc);
      ws[P_OFF + (size_t)i * 64 + oc] = acc;
      ws[Q_OFF + (size_t)i * 64 + oc] = qacc;
    }
    return;
  }

  // ---------------- weight fold for mlp (W1T/B1/W2T/B2) ------------------
  {
    int i = (blk - 4096) * 256 + tid + 4352;
    if (i < 8448) {
      int j = i - 4352; int oc = j & 63, ic = j >> 6;
      float s = g1[oc] * rsqrtf(rv1[oc] + EPSV);
      ws[i] = w1[oc * 64 + ic] * s;
    } else if (i < 8512) {
      int oc = i - 8448;
      float s = g1[oc] * rsqrtf(rv1[oc] + EPSV);
      ws[i] = (b1[oc] - rm1[oc]) * s + be1[oc];
    } else if (i < 16704) {
      int j = i - 8512; int ic = j >> 7, oc = j & 127;
      float s = g2[oc] * rsqrtf(rv2[oc] + EPSV);
      ws[i] = w2[oc * 64 + ic] * s;               // w2t [ic][oc]
    } else if (i < 16832) {
      int oc = i - 16704;
      float s = g2[oc] * rsqrtf(rv2[oc] + EPSV);
      ws[i] = (b2[oc] - rm2[oc]) * s + be2[oc];
    }
  }
}

// MLP v8 restored (passed in R6, absmax identical; inferred ~79-81us vs v10's
// measured 89.5): block = 256 thr = 8 queries = 128 pairs; thread tile 4p x 8oc.
// LDS: A[64][128] (32 KB, h0 then h1 in place) + ONE 8 KB W-chunk cycled
// through 6 chunks (W1a,W1b,W2p0a,W2p0b,W2p1a,W2p1b) with register preloads
// = 40 KB -> 4 blocks/CU = 4 waves/SIMD. R10 evidence: the 3->4 blocks/CU
// occupancy step is the mlp lever (DS-ratio retiles measured null twice).
// Accumulation order bias + ic 0..63 sequential -> bit-identical results.
__global__ __launch_bounds__(256, 4) void mlp_kernel(
    const float* __restrict__ wbuf, const int* __restrict__ knn,
    float* __restrict__ out) {
  __shared__ __align__(16) float Ash[64 * 128];   // 32 KB [ic][p]
  __shared__ __align__(16) float Wsh[32 * 64];    // 8 KB chunk [icLocal][oc]
  int tid = threadIdx.x;
  int qblk = blockIdx.x << 3;                     // 8 flat queries per block

  const float4* w1g = (const float4*)(wbuf + W1T_OFF);   // [64][16 f4]
  const float4* w2g = (const float4*)(wbuf + W2T_OFF);   // [64][32 f4]
  float4* wl = (float4*)Wsh;

  // W2 chunk (pass p, ic-half h) entry e in [0,512): row 32h+(e>>4), colf4 16p+(e&15)
#define W2IDX(e, p, h) ((((h) << 5) + ((e) >> 4)) * 32 + ((p) << 4) + ((e) & 15))

  // ---- preload W1a ----
  float4 s0 = w1g[tid];
  float4 s1 = w1g[256 + tid];

  // ---- h0: pair p = tid&127, ic-half = tid>>7 ----
  {
    int p = tid & 127, half = tid >> 7;
    int q = qblk + (p >> 4);
    int k = p & 15;
    int src = knn[q * KNN_K + k];                 // coalesced across 128 threads
    int srow = (q & ~(NPT - 1)) + src;
    const float4* Pp = (const float4*)(wbuf + P_OFF + (size_t)srow * 64 + half * 32);
    const float4* Qp = (const float4*)(wbuf + Q_OFF + (size_t)q * 64 + half * 32);
#pragma unroll
    for (int j = 0; j < 8; ++j) {
      float4 pv = Pp[j];
      float4 qv = Qp[j];
      int ic = half * 32 + j * 4;
      Ash[(ic + 0) * 128 + p] = fmaxf(pv.x - qv.x, 0.0f);
      Ash[(ic + 1) * 128 + p] = fmaxf(pv.y - qv.y, 0.0f);
      Ash[(ic + 2) * 128 + p] = fmaxf(pv.z - qv.z, 0.0f);
      Ash[(ic + 3) * 128 + p] = fmaxf(pv.w - qv.w, 0.0f);
    }
  }
  // write W1a; preload W1b
  wl[tid] = s0; wl[256 + tid] = s1;
  s0 = w1g[512 + tid]; s1 = w1g[768 + tid];
  __syncthreads();                                 // S1: h0 + W1a visible

  int og = tid & 7, pg = tid >> 3;                 // 32 pgrp x 8 ogrp
  const float* Arow = Ash + 4 * pg;
  const float* Wrow = Wsh + 8 * og;
  float acc[4][8];                                 // [pair][oc]

#define GEMM32(R0)                                                        \
  _Pragma("unroll 8")                                                     \
  for (int ic = 0; ic < 32; ++ic) {                                       \
    float4 a0 = *(const float4*)(Arow + ((R0) + ic) * 128);               \
    float4 wv0 = *(const float4*)(Wrow + ic * 64);                        \
    float4 wv1 = *(const float4*)(Wrow + ic * 64 + 4);                    \
    float av[4] = {a0.x, a0.y, a0.z, a0.w};                               \
    float wv[8] = {wv0.x, wv0.y, wv0.z, wv0.w, wv1.x, wv1.y, wv1.z, wv1.w};\
    _Pragma("unroll")                                                     \
    for (int ii = 0; ii < 4; ++ii)                                        \
      _Pragma("unroll")                                                   \
      for (int jj = 0; jj < 8; ++jj) acc[ii][jj] = fmaf(av[ii], wv[jj], acc[ii][jj]); \
  }

  // ---- layer 1 ----
  {
    float4 b0v = *(const float4*)(wbuf + B1_OFF + 8 * og);
    float4 b1v = *(const float4*)(wbuf + B1_OFF + 8 * og + 4);
    float bj[8] = {b0v.x, b0v.y, b0v.z, b0v.w, b1v.x, b1v.y, b1v.z, b1v.w};
#pragma unroll
    for (int i = 0; i < 4; ++i)
#pragma unroll
      for (int j = 0; j < 8; ++j) acc[i][j] = bj[j];
  }
  GEMM32(0)                                        // W1a: ic 0..31
  __syncthreads();                                 // S2: W1a reads done
  wl[tid] = s0; wl[256 + tid] = s1;                // write W1b
  s0 = w2g[W2IDX(tid, 0, 0)]; s1 = w2g[W2IDX(tid + 256, 0, 0)];
  __syncthreads();                                 // S3: W1b visible
  GEMM32(32)                                       // W1b: ic 32..63
  __syncthreads();                                 // S4: all Ash(h0)+W1b reads done

  // h1 -> A[oc][p] (write throughput-limited, once per layer: accepted)
#pragma unroll
  for (int j = 0; j < 8; ++j) {
    int oc = 8 * og + j;
    *(float4*)(Ash + oc * 128 + 4 * pg) =
        make_float4(fmaxf(acc[0][j], 0.0f), fmaxf(acc[1][j], 0.0f),
                    fmaxf(acc[2][j], 0.0f), fmaxf(acc[3][j], 0.0f));
  }
  // stage W2p0a from regs; preload W2p0b
  wl[tid] = s0; wl[256 + tid] = s1;
  s0 = w2g[W2IDX(tid, 0, 1)]; s1 = w2g[W2IDX(tid + 256, 0, 1)];
  __syncthreads();                                 // S5: h1 + W2p0a visible

  int qout = qblk + (pg >> 2);
  float* obase = out + (size_t)qout * 128 + 8 * og;

  // ---- layer 2 pass 0 (oc 0..63) ----
  {
    float4 b0v = *(const float4*)(wbuf + B2_OFF + 8 * og);
    float4 b1v = *(const float4*)(wbuf + B2_OFF + 8 * og + 4);
    float bj[8] = {b0v.x, b0v.y, b0v.z, b0v.w, b1v.x, b1v.y, b1v.z, b1v.w};
#pragma unroll
    for (int i = 0; i < 4; ++i)
#pragma unroll
      for (int j = 0; j < 8; ++j) acc[i][j] = bj[j];
  }
  GEMM32(0)                                        // W2p0a: ic 0..31
  __syncthreads();                                 // S6
  wl[tid] = s0; wl[256 + tid] = s1;                // write W2p0b
  s0 = w2g[W2IDX(tid, 1, 0)]; s1 = w2g[W2IDX(tid + 256, 1, 0)];
  __syncthreads();                                 // S7
  GEMM32(32)                                       // W2p0b: ic 32..63
  {
    float m[8];
#pragma unroll
    for (int j = 0; j < 8; ++j) {
      float v = fmaxf(fmaxf(acc[0][j], acc[1][j]), fmaxf(acc[2][j], acc[3][j]));
      v = fmaxf(v, 0.0f);
      v = fmaxf(v, __shfl_xor(v, 8));              // pg bit 0
      m[j] = fmaxf(v, __shfl_xor(v, 16));          // pg bit 1
    }
    if ((pg & 3) == 0) {
      *(float4*)(obase)     = make_float4(m[0], m[1], m[2], m[3]);
      *(float4*)(obase + 4) = make_float4(m[4], m[5], m[6], m[7]);
    }
  }
  __syncthreads();                                 // S8
  wl[tid] = s0; wl[256 + tid] = s1;                // write W2p1a
  s0 = w2g[W2IDX(tid, 1, 1)]; s1 = w2g[W2IDX(tid + 256, 1, 1)];
  __syncthreads();                                 // S9

  // ---- layer 2 pass 1 (oc 64..127) ----
  {
    float4 b0v = *(const float4*)(wbuf + B2_OFF + 64 + 8 * og);
    float4 b1v = *(const float4*)(wbuf + B2_OFF + 64 + 8 * og + 4);
    float bj[8] = {b0v.x, b0v.y, b0v.z, b0v.w, b1v.x, b1v.y, b1v.z, b1v.w};
#pragma unroll
    for (int i = 0; i < 4; ++i)
#pragma unroll
      for (int j = 0; j < 8; ++j) acc[i][j] = bj[j];
  }
  GEMM32(0)                                        // W2p1a: ic 0..31
  __syncthreads();                                 // S10
  wl[tid] = s0; wl[256 + tid] = s1;                // write W2p1b
  __syncthreads();                                 // S11
  GEMM32(32)                                       // W2p1b: ic 32..63
  {
    float m[8];
#pragma unroll
    for (int j = 0; j < 8; ++j) {
      float v = fmaxf(fmaxf(acc[0][j], acc[1][j]), fmaxf(acc[2][j], acc[3][j]));
      v = fmaxf(v, 0.0f);
      v = fmaxf(v, __shfl_xor(v, 8));
      m[j] = fmaxf(v, __shfl_xor(v, 16));
    }
    if ((pg & 3) == 0) {
      *(float4*)(obase + 64)     = make_float4(m[0], m[1], m[2], m[3]);
      *(float4*)(obase + 64 + 4) = make_float4(m[4], m[5], m[6], m[7]);
    }
  }
#undef GEMM32
#undef W2IDX
}

extern "C" void kernel_launch(void* const* d_in, const int* in_sizes, int n_in,
                              void* d_out, int out_size, void* d_ws, size_t ws_size,
                              hipStream_t stream) {
  const float* xyz    = (const float*)d_in[0];
  const float* points = (const float*)d_in[1];
  float* wsF = (float*)d_ws;
  int* idxBuf = (int*)(wsF + IDX_OFF);

  mega_kernel<<<4145, 256, 0, stream>>>(
      xyz, points,
      (const float*)d_in[2],  (const float*)d_in[3],  (const float*)d_in[4],
      (const float*)d_in[5],  (const float*)d_in[6],  (const float*)d_in[7],
      (const float*)d_in[8],  (const float*)d_in[9],  (const float*)d_in[10],
      (const float*)d_in[11], (const float*)d_in[12], (const float*)d_in[13],
      (const float*)d_in[14], (const float*)d_in[15], (const float*)d_in[16],
      (const float*)d_in[17], (const float*)d_in[18], (const float*)d_in[19],
      wsF, idxBuf);
  mlp_kernel<<<2048, 256, 0, stream>>>(wsF, idxBuf, (float*)d_out);
}